// Round 1
// baseline (230.646 us; speedup 1.0000x reference)
//
#include <hip/hip_runtime.h>

#define NB 4
#define NN 1024
#define CC 64

typedef float f4_native __attribute__((ext_vector_type(4)));

// Kernel 0: per-batch column sum of x, then ysb[b][o] = dot(xsum, W2[o,:]) + bias[o]
__global__ void k_sum(const float* __restrict__ x, const float* __restrict__ W2,
                      const float* __restrict__ bias, float* __restrict__ ysb) {
    const int b = blockIdx.x;
    const int t = threadIdx.x;
    const int c = t & 63, g = t >> 6;   // 4 n-groups x 64 channels
    __shared__ float sPart[4][64];
    __shared__ float sXsum[64];
    float acc = 0.f;
    const float* xb = x + (size_t)b * NN * CC;
    for (int n = g; n < NN; n += 4)
        acc += xb[n * CC + c];
    sPart[g][c] = acc;
    __syncthreads();
    if (t < 64)
        sXsum[t] = sPart[0][t] + sPart[1][t] + sPart[2][t] + sPart[3][t];
    __syncthreads();
    if (t < 64) {
        float v = bias[t];               // bias shape (64,1) -> bias[o]
        const float* w = W2 + t * CC;
        #pragma unroll 8
        for (int cc = 0; cc < CC; ++cc) v += sXsum[cc] * w[cc];
        ysb[b * CC + t] = v;
    }
}

// Kernel 1: yc[b,n,o] = sum_c x[b,n,c]*W0[o,c]
//           yr2[b,n,o] = sum_c x[b,n,c]*W1[o,c] + ysb[b,o]
__global__ void k_gemm(const float* __restrict__ x, const float* __restrict__ W0,
                       const float* __restrict__ W1, const float* __restrict__ ysb,
                       float* __restrict__ yc, float* __restrict__ yr2) {
    __shared__ float sW0[64][65];   // +1 pad: unpadded stride-64 reads are a 32-way bank conflict
    __shared__ float sW1[64][65];
    __shared__ float sX[4][64];
    const int t = threadIdx.x;
    const int blocksPerB = NN / 4;
    const int b = blockIdx.x / blocksPerB;
    const int n0 = (blockIdx.x % blocksPerB) * 4;
    for (int idx = t; idx < 64 * 64; idx += 256) {
        sW0[idx >> 6][idx & 63] = W0[idx];
        sW1[idx >> 6][idx & 63] = W1[idx];
    }
    const int o = t & 63, r = t >> 6;
    sX[r][o] = x[((size_t)(b * NN + n0 + r)) * CC + o];
    __syncthreads();
    float a0 = 0.f, a1 = 0.f;
    #pragma unroll
    for (int c = 0; c < 64; ++c) {
        const float xv = sX[r][c];
        a0 += xv * sW0[o][c];
        a1 += xv * sW1[o][c];
    }
    const size_t oidx = ((size_t)(b * NN + n0 + r)) * CC + o;
    yc[oidx]  = a0;
    yr2[oidx] = a1 + ysb[b * CC + o];
}

// Kernel 2: out[b,i,j,:] = yc[b,j,:] + yr2[b,i,:]  (float4, nontemporal streaming stores)
// One block per (b,i) row. Thread t: o4 = t&15 (fixed -> yr2 frag in register), j strided by 16.
__global__ void k_bcast(const float4* __restrict__ yc4, const float4* __restrict__ yr4,
                        float4* __restrict__ out4) {
    const int t  = threadIdx.x;
    const int o4 = t & 15;
    const int j0 = t >> 4;
    const int b  = blockIdx.x >> 10;     // / NN
    const int i  = blockIdx.x & (NN - 1);
    float4 yr = yr4[(size_t)(b * NN + i) * 16 + o4];
    const float4* ycb = yc4 + (size_t)b * NN * 16;
    float4* ob = out4 + (size_t)(b * NN + i) * (NN * 16);
    #pragma unroll 4
    for (int j = j0; j < NN; j += 16) {
        float4 v = ycb[j * 16 + o4];
        v.x += yr.x; v.y += yr.y; v.z += yr.z; v.w += yr.w;
        __builtin_nontemporal_store(*(const f4_native*)&v, (f4_native*)&ob[j * 16 + o4]);
    }
}

extern "C" void kernel_launch(void* const* d_in, const int* in_sizes, int n_in,
                              void* d_out, int out_size, void* d_ws, size_t ws_size,
                              hipStream_t stream) {
    const float* x    = (const float*)d_in[0];
    // d_in[1] = adj (unused by forward)
    const float* W0   = (const float*)d_in[2];
    const float* W1   = (const float*)d_in[3];
    const float* W2   = (const float*)d_in[4];
    const float* bias = (const float*)d_in[5];
    float* out = (float*)d_out;

    float* ws  = (float*)d_ws;
    float* ysb = ws;                       // NB*CC      = 256 floats
    float* yc  = ws + 256;                 // NB*NN*CC   = 262144 floats
    float* yr2 = ws + 256 + NB * NN * CC;  // NB*NN*CC   = 262144 floats

    k_sum<<<NB, 256, 0, stream>>>(x, W2, bias, ysb);
    k_gemm<<<NB * NN / 4, 256, 0, stream>>>(x, W0, W1, ysb, yc, yr2);
    k_bcast<<<NB * NN, 256, 0, stream>>>((const float4*)yc, (const float4*)yr2, (float4*)out);
}

// Round 4
// 221.288 us; speedup vs baseline: 1.0423x; 1.0423x over previous
//
#include <hip/hip_runtime.h>

#define NB 4
#define NN 1024
#define CC 64
#define BPB (NN / 4)   // gemm blocks per batch = 256

typedef float f4_native __attribute__((ext_vector_type(4)));

// Kernel 1: per 4-row block:
//   yc[b,n,o] = sum_c x[b,n,c]*W0[o,c]
//   yr[b,n,o] = sum_c x[b,n,c]*W1[o,c]
//   partials[blk,c] = sum over the block's 4 rows of x[.,c]
__global__ void k_gemm(const float* __restrict__ x, const float* __restrict__ W0,
                       const float* __restrict__ W1,
                       float* __restrict__ yc, float* __restrict__ yr,
                       float* __restrict__ partials) {
    __shared__ float sW0[64][65];   // +1 pad: stride-64 col reads would be 32-way bank conflict
    __shared__ float sW1[64][65];
    __shared__ float sX[4][64];
    const int t = threadIdx.x;
    const int b = blockIdx.x / BPB;
    const int n0 = (blockIdx.x % BPB) * 4;
    for (int idx = t; idx < 64 * 64; idx += 256) {
        sW0[idx >> 6][idx & 63] = W0[idx];
        sW1[idx >> 6][idx & 63] = W1[idx];
    }
    const int o = t & 63, r = t >> 6;
    sX[r][o] = x[((size_t)(b * NN + n0 + r)) * CC + o];
    __syncthreads();
    float a0 = 0.f, a1 = 0.f;
    #pragma unroll
    for (int c = 0; c < 64; ++c) {
        const float xv = sX[r][c];
        a0 += xv * sW0[o][c];
        a1 += xv * sW1[o][c];
    }
    const size_t oidx = ((size_t)(b * NN + n0 + r)) * CC + o;
    yc[oidx] = a0;
    yr[oidx] = a1;
    if (r == 0)   // threads 0..63: column partial sum of this block's 4 rows
        partials[(size_t)blockIdx.x * 64 + o] =
            sX[0][o] + sX[1][o] + sX[2][o] + sX[3][o];
}

// Kernel 2 (tiny): reduce partials per batch -> xsum, then ysb[b,o] = xsum.W2[o,:] + bias[o]
__global__ void k_ysb(const float* __restrict__ partials, const float* __restrict__ W2,
                      const float* __restrict__ bias, float* __restrict__ ysb) {
    const int b = blockIdx.x;
    const int t = threadIdx.x;
    const int c = t & 63, g = t >> 6;   // 4 groups x 64 channels
    __shared__ float sPart[4][64];
    __shared__ float sXsum[64];
    float acc = 0.f;
    const float* pb = partials + (size_t)b * BPB * 64;
    for (int blk = g; blk < BPB; blk += 4)
        acc += pb[blk * 64 + c];
    sPart[g][c] = acc;
    __syncthreads();
    if (t < 64)
        sXsum[t] = sPart[0][t] + sPart[1][t] + sPart[2][t] + sPart[3][t];
    __syncthreads();
    if (t < 64) {
        float v = bias[t];               // bias shape (64,1) -> bias[o]
        const float* w = W2 + t * CC;
        #pragma unroll 8
        for (int cc = 0; cc < CC; ++cc) v += sXsum[cc] * w[cc];
        ysb[b * CC + t] = v;
    }
}

// Kernel 3: out[b,i,j,:] = yc[b,j,:] + yr[b,i,:] + ysb[b,:]  (float4, nontemporal stores)
// One block per (b,i) row; thread t holds its (yr+ysb) float4 in register across all j.
__global__ void k_bcast(const float4* __restrict__ yc4, const float4* __restrict__ yr4,
                        const float4* __restrict__ ysb4, float4* __restrict__ out4) {
    const int t  = threadIdx.x;
    const int o4 = t & 15;
    const int j0 = t >> 4;
    const int b  = blockIdx.x >> 10;     // / NN
    const int i  = blockIdx.x & (NN - 1);
    float4 yr = yr4[(size_t)(b * NN + i) * 16 + o4];
    float4 ys = ysb4[b * 16 + o4];
    yr.x += ys.x; yr.y += ys.y; yr.z += ys.z; yr.w += ys.w;
    const float4* ycb = yc4 + (size_t)b * NN * 16;
    float4* ob = out4 + (size_t)(b * NN + i) * (NN * 16);
    #pragma unroll 4
    for (int j = j0; j < NN; j += 16) {
        float4 v = ycb[j * 16 + o4];
        v.x += yr.x; v.y += yr.y; v.z += yr.z; v.w += yr.w;
        __builtin_nontemporal_store(*(const f4_native*)&v, (f4_native*)&ob[j * 16 + o4]);
    }
}

extern "C" void kernel_launch(void* const* d_in, const int* in_sizes, int n_in,
                              void* d_out, int out_size, void* d_ws, size_t ws_size,
                              hipStream_t stream) {
    const float* x    = (const float*)d_in[0];
    // d_in[1] = adj (unused by forward)
    const float* W0   = (const float*)d_in[2];
    const float* W1   = (const float*)d_in[3];
    const float* W2   = (const float*)d_in[4];
    const float* bias = (const float*)d_in[5];
    float* out = (float*)d_out;

    float* ws       = (float*)d_ws;
    float* ysb      = ws;                                   // 256 floats
    float* yc       = ws + 256;                             // 262144 floats
    float* yr       = yc + NB * NN * CC;                    // 262144 floats
    float* partials = yr + NB * NN * CC;                    // 1024*64 = 65536 floats

    k_gemm<<<NB * BPB, 256, 0, stream>>>(x, W0, W1, yc, yr, partials);
    k_ysb<<<NB, 256, 0, stream>>>(partials, W2, bias, ysb);
    k_bcast<<<NB * NN, 256, 0, stream>>>((const float4*)yc, (const float4*)yr,
                                         (const float4*)ysb, (float4*)out);
}